// Round 3
// baseline (162.846 us; speedup 1.0000x reference)
//
#include <hip/hip_runtime.h>
#include <hip/hip_bf16.h>
#include <stdint.h>

#define LRELU_ALPHA 0.2f
#define NEG_INF -9000000000000000.0f
#define NB 32768
#define NTASKS (NB/16)
#define GRID 1024

typedef float f32x4 __attribute__((ext_vector_type(4)));
typedef short s16x8 __attribute__((ext_vector_type(8)));

__device__ __forceinline__ unsigned short f2bf(float f){
  unsigned int u = __float_as_uint(f);
  u += 0x7fffu + ((u >> 16) & 1u);   // round-to-nearest-even
  return (unsigned short)(u >> 16);
}

// ws layout: ushort [0,16384): W^T bf16 swizzled (64 cols x 256 k)
//            ushort [16384,20480): e-tile bf16 swizzled (16 cols x 256 k; col0=W@aS, col1=W@aD, rest 0)
//            float  [10240,10432) (byte 40960+): v1,v2,v3 = W2eff @ {a2S, a2D, fc_w} (3 x 64 f32)
__global__ void prep_kernel(const float* __restrict__ W, const float* __restrict__ W2,
                            const float* __restrict__ a, const float* __restrict__ a2,
                            const float* __restrict__ fc_w,
                            unsigned short* __restrict__ wsp){
  int t = blockIdx.x * blockDim.x + threadIdx.x;
  if (t < 64*256){
    int o = t & 63, k = t >> 6;
    wsp[o*256 + (k ^ ((o & 7) << 3))] = f2bf(W[k*64 + o]);
  }
  if (t < 16*256){
    int o = t & 15, k = t >> 4;
    float v = 0.f;
    if (o == 0){ for (int c = 0; c < 64; ++c) v += W[k*64 + c]*a[c]; }
    else if (o == 1){ for (int c = 0; c < 64; ++c) v += W[k*64 + c]*a[64 + c]; }
    wsp[16384 + o*256 + (k ^ ((o & 7) << 3))] = f2bf(v);
  }
  if (t < 192){
    int which = t >> 6, c = t & 63;
    const float* vec = (which == 0) ? a2 : (which == 1) ? (a2 + 64) : fc_w;
    float s = 0.f;
    for (int o = 0; o < 64; ++o){
      float w2e = 0.f;
      #pragma unroll
      for (int h = 0; h < 8; ++h) w2e += W2[(h*64 + c)*64 + o];
      s += w2e * vec[o];
    }
    ((float*)wsp)[10240 + t] = s;
  }
}

__launch_bounds__(256, 4)
__global__ void gat_kernel(const float* __restrict__ x, const float* __restrict__ adj,
                           const float* __restrict__ fc_b,
                           const unsigned short* __restrict__ wsp,
                           float* __restrict__ out){
  // LDS: [0,16384) W^T ; [16384,20480) e-tile  (40 KB -> 4 blocks/CU)
  __shared__ __align__(16) unsigned short smem[20480];
  const int tid = threadIdx.x;
  const int p  = tid & 15;        // A-row / B-col / C-col lane index
  const int g  = (tid >> 4) & 3;  // 16-lane group within wave (owns graph g)
  const int wv = tid >> 6;        // wave id in block
  const int lbase = tid & 48;     // wave-relative group base lane

  // ---- issue iteration-0 x/adj loads FIRST (longest pole) ----
  float4 xb[8][2];
  float adv;
  {
    const int b0 = blockIdx.x*16 + wv*4;
    const float* xrow = x + ((size_t)(b0 + (p >> 2))*4 + (p & 3))*256 + g*8;
    #pragma unroll
    for (int kk = 0; kk < 8; ++kk){
      xb[kk][0] = *(const float4*)(xrow + kk*32);
      xb[kk][1] = *(const float4*)(xrow + kk*32 + 4);
    }
    adv = adj[(size_t)(b0 + g)*16 + p];
  }

  // ---- stage W + e-tile into LDS (L2-resident source; overlaps x latency) ----
  {
    const uint4* src = (const uint4*)wsp;
    uint4* dst = (uint4*)smem;
    #pragma unroll
    for (int i = 0; i < 10; ++i) dst[tid + 256*i] = src[tid + 256*i];
  }

  // per-lane GEMV vectors for layer 2
  const float* vf = (const float*)wsp;
  float v1l[4], v2l[4], v3l[4];
  #pragma unroll
  for (int ct = 0; ct < 4; ++ct){
    v1l[ct] = vf[10240 +   0 + ct*16 + p];
    v2l[ct] = vf[10240 +  64 + ct*16 + p];
    v3l[ct] = vf[10240 + 128 + ct*16 + p];
  }
  const float fcb = fc_b[0];
  __syncthreads();

  for (int it = blockIdx.x; it < NTASKS; it += GRID){
    const int b0 = it*16 + wv*4;                 // wave's 4 graphs: b0..b0+3
    const float adjv = adv;                      // adj[b0+g][i=p>>2][j=p&3] (prefetched)

    // -------- GEMM1: [Wh | fs fd] = x @ [W | waS waD] (16 x 80, K=256) --------
    f32x4 acc[4], acce;
    #pragma unroll
    for (int ct = 0; ct < 4; ++ct) acc[ct] = (f32x4){0.f,0.f,0.f,0.f};
    acce = (f32x4){0.f,0.f,0.f,0.f};
    #pragma unroll
    for (int kk = 0; kk < 8; ++kk){
      float4 f0 = xb[kk][0];
      float4 f1 = xb[kk][1];
      union { s16x8 v; __hip_bfloat162 h2[4]; } af;
      af.h2[0] = __float22bfloat162_rn(make_float2(f0.x, f0.y));
      af.h2[1] = __float22bfloat162_rn(make_float2(f0.z, f0.w));
      af.h2[2] = __float22bfloat162_rn(make_float2(f1.x, f1.y));
      af.h2[3] = __float22bfloat162_rn(make_float2(f1.z, f1.w));
      const int kb = kk*32 + g*8;
      #pragma unroll
      for (int ct = 0; ct < 4; ++ct){
        const int o = ct*16 + p;
        s16x8 bf = *(const s16x8*)&smem[o*256 + (kb ^ ((o & 7) << 3))];
        acc[ct] = __builtin_amdgcn_mfma_f32_16x16x32_bf16(af.v, bf, acc[ct], 0, 0, 0);
      }
      s16x8 ef = *(const s16x8*)&smem[16384 + p*256 + (kb ^ ((p & 7) << 3))];
      acce = __builtin_amdgcn_mfma_f32_16x16x32_bf16(af.v, ef, acce, 0, 0, 0);
    }
    // acc[ct][r] = Wh[4g+r][ct*16+p] ; acce[r] at lane(0,g)=fs[4g+r], lane(1,g)=fd[4g+r]

    // ---- issue next iteration's loads NOW; they fly during the epilogue ----
    {
      const int itn = it + GRID;
      if (itn < NTASKS){
        const int b0n = itn*16 + wv*4;
        const float* xrow = x + ((size_t)(b0n + (p >> 2))*4 + (p & 3))*256 + g*8;
        #pragma unroll
        for (int kk = 0; kk < 8; ++kk){
          xb[kk][0] = *(const float4*)(xrow + kk*32);
          xb[kk][1] = *(const float4*)(xrow + kk*32 + 4);
        }
        adv = adj[(size_t)(b0n + g)*16 + p];
      }
    }

    // -------- layer-1 attention (group g = graph b0+g) --------
    float fsr[4], fdr[4];
    #pragma unroll
    for (int r = 0; r < 4; ++r){
      fsr[r] = __shfl(acce[r], lbase + 0);
      fdr[r] = __shfl(acce[r], lbase + 1);
    }
    float fsi = (p & 8) ? ((p & 4) ? fsr[3] : fsr[2]) : ((p & 4) ? fsr[1] : fsr[0]);
    float fdj = (p & 2) ? ((p & 1) ? fdr[3] : fdr[2]) : ((p & 1) ? fdr[1] : fdr[0]);
    float ev = fsi + fdj;
    ev = (ev > 0.f) ? ev : LRELU_ALPHA*ev;
    ev = (adjv > 0.f) ? ev : NEG_INF;
    float mx = fmaxf(ev, __shfl_xor(ev, 1));
    mx = fmaxf(mx, __shfl_xor(mx, 2));
    float pe = __expf(ev - mx);
    float se = pe + __shfl_xor(pe, 1);
    se += __shfl_xor(se, 2);
    const float att = pe / se;   // att[i=p>>2][j=p&3] of graph b0+g

    // -------- hp = att @ Wh ; h1 = elu(hp), kept in f32 registers --------
    float h[4][4];  // h[ct][r] = h1[4g+r][ct*16+p]
    #pragma unroll
    for (int r = 0; r < 4; ++r){
      float b0a = __shfl(att, lbase + r*4 + 0);
      float b1a = __shfl(att, lbase + r*4 + 1);
      float b2a = __shfl(att, lbase + r*4 + 2);
      float b3a = __shfl(att, lbase + r*4 + 3);
      #pragma unroll
      for (int ct = 0; ct < 4; ++ct){
        float hp = b0a*acc[ct][0] + b1a*acc[ct][1] + b2a*acc[ct][2] + b3a*acc[ct][3];
        h[ct][r] = (hp > 0.f) ? hp : (__expf(hp) - 1.0f);
      }
    }

    // -------- layer 2 as GEMV: fs20, fd2[r], sv[r] = h1 . v{1,2,3} --------
    float fd2[4], sv[4], fs20 = 0.f;
    #pragma unroll
    for (int r = 0; r < 4; ++r){
      float s1 = 0.f, s2 = 0.f;
      #pragma unroll
      for (int ct = 0; ct < 4; ++ct){ s1 += h[ct][r]*v2l[ct]; s2 += h[ct][r]*v3l[ct]; }
      fd2[r] = s1; sv[r] = s2;
    }
    #pragma unroll
    for (int ct = 0; ct < 4; ++ct) fs20 += h[ct][0]*v1l[ct];
    #pragma unroll
    for (int msk = 1; msk < 16; msk <<= 1){
      #pragma unroll
      for (int r = 0; r < 4; ++r){
        fd2[r] += __shfl_xor(fd2[r], msk);
        sv[r]  += __shfl_xor(sv[r],  msk);
      }
      fs20 += __shfl_xor(fs20, msk);
    }

    // -------- layer-2 attention (row 0 only) + fc --------
    float e2[4];
    #pragma unroll
    for (int j = 0; j < 4; ++j){
      float adj0 = __shfl(adjv, lbase + j);     // adj[b][0][j]
      float tv = fs20 + fd2[j];
      tv = (tv > 0.f) ? tv : LRELU_ALPHA*tv;
      e2[j] = (adj0 > 0.f) ? tv : NEG_INF;
    }
    float m2 = fmaxf(fmaxf(e2[0], e2[1]), fmaxf(e2[2], e2[3]));
    float s2s = 0.f, ov = 0.f;
    #pragma unroll
    for (int j = 0; j < 4; ++j){
      float pj = __expf(e2[j] - m2);
      s2s += pj; ov += pj*sv[j];
    }
    if (p == 0) out[b0 + g] = ov/s2s + fcb;
  }
}

extern "C" void kernel_launch(void* const* d_in, const int* in_sizes, int n_in,
                              void* d_out, int out_size, void* d_ws, size_t ws_size,
                              hipStream_t stream){
  (void)in_sizes; (void)n_in; (void)out_size; (void)ws_size;
  const float* x   = (const float*)d_in[0];
  const float* adj = (const float*)d_in[1];
  const float* W   = (const float*)d_in[2];
  const float* a   = (const float*)d_in[3];
  const float* W2  = (const float*)d_in[4];
  const float* a2  = (const float*)d_in[5];
  const float* fcw = (const float*)d_in[6];
  const float* fcb = (const float*)d_in[7];
  float* out = (float*)d_out;
  unsigned short* wsp = (unsigned short*)d_ws;

  hipLaunchKernelGGL(prep_kernel, dim3(64), dim3(256), 0, stream, W, W2, a, a2, fcw, wsp);
  hipLaunchKernelGGL(gat_kernel, dim3(GRID), dim3(256), 0, stream,
                     x, adj, fcb, wsp, out);
}

// Round 4
// 120.373 us; speedup vs baseline: 1.3528x; 1.3528x over previous
//
#include <hip/hip_runtime.h>
#include <hip/hip_bf16.h>
#include <stdint.h>

#define LRELU_ALPHA 0.2f
#define NEG_INF -9000000000000000.0f
#define NB 32768
#define NTASKS (NB/16)
#define GRID 768

typedef float f32x4 __attribute__((ext_vector_type(4)));
typedef short s16x8 __attribute__((ext_vector_type(8)));

__device__ __forceinline__ unsigned short f2bf(float f){
  unsigned int u = __float_as_uint(f);
  u += 0x7fffu + ((u >> 16) & 1u);   // round-to-nearest-even
  return (unsigned short)(u >> 16);
}

// ws layout: ushort [0,16384): W^T bf16 swizzled (64 cols x 256 k)
//            ushort [16384,20480): e-tile bf16 swizzled (16 cols x 256 k; col0=W@aS, col1=W@aD, rest 0)
//            float  [10240,10432) (byte 40960+): v1,v2,v3 = W2eff @ {a2S, a2D, fc_w} (3 x 64 f32)
__global__ void prep_kernel(const float* __restrict__ W, const float* __restrict__ W2,
                            const float* __restrict__ a, const float* __restrict__ a2,
                            const float* __restrict__ fc_w,
                            unsigned short* __restrict__ wsp){
  int t = blockIdx.x * blockDim.x + threadIdx.x;
  if (t < 64*256){
    int o = t & 63, k = t >> 6;
    wsp[o*256 + (k ^ ((o & 7) << 3))] = f2bf(W[k*64 + o]);
  }
  if (t < 16*256){
    int o = t & 15, k = t >> 4;
    float v = 0.f;
    if (o == 0){ for (int c = 0; c < 64; ++c) v += W[k*64 + c]*a[c]; }
    else if (o == 1){ for (int c = 0; c < 64; ++c) v += W[k*64 + c]*a[64 + c]; }
    wsp[16384 + o*256 + (k ^ ((o & 7) << 3))] = f2bf(v);
  }
  if (t < 192){
    int which = t >> 6, c = t & 63;
    const float* vec = (which == 0) ? a2 : (which == 1) ? (a2 + 64) : fc_w;
    float s = 0.f;
    for (int o = 0; o < 64; ++o){
      float w2e = 0.f;
      #pragma unroll
      for (int h = 0; h < 8; ++h) w2e += W2[(h*64 + c)*64 + o];
      s += w2e * vec[o];
    }
    ((float*)wsp)[10240 + t] = s;
  }
}

__launch_bounds__(256, 3)   // 3 waves/EU: VGPR cap ~170 — fits the 64-reg prefetch buffer, NO SPILL
__global__ void gat_kernel(const float* __restrict__ x, const float* __restrict__ adj,
                           const float* __restrict__ fc_b,
                           const unsigned short* __restrict__ wsp,
                           float* __restrict__ out){
  // LDS: [0,16384) W^T ; [16384,20480) e-tile  (40 KB)
  __shared__ __align__(16) unsigned short smem[20480];
  const int tid = threadIdx.x;
  const int p  = tid & 15;        // A-row / B-col / C-col lane index
  const int g  = (tid >> 4) & 3;  // 16-lane group within wave (owns graph g)
  const int wv = tid >> 6;        // wave id in block
  const int lbase = tid & 48;     // wave-relative group base lane

  // ---- issue iteration-0 x/adj loads FIRST (longest pole) ----
  float4 xb[8][2];
  float adv;
  {
    const int b0 = blockIdx.x*16 + wv*4;
    const float* xrow = x + ((size_t)(b0 + (p >> 2))*4 + (p & 3))*256 + g*8;
    #pragma unroll
    for (int kk = 0; kk < 8; ++kk){
      xb[kk][0] = *(const float4*)(xrow + kk*32);
      xb[kk][1] = *(const float4*)(xrow + kk*32 + 4);
    }
    adv = adj[(size_t)(b0 + g)*16 + p];
  }

  // ---- stage W + e-tile into LDS (L2-resident source; overlaps x latency) ----
  {
    const uint4* src = (const uint4*)wsp;
    uint4* dst = (uint4*)smem;
    #pragma unroll
    for (int i = 0; i < 10; ++i) dst[tid + 256*i] = src[tid + 256*i];
  }

  // per-lane GEMV vectors for layer 2
  const float* vf = (const float*)wsp;
  float v1l[4], v2l[4], v3l[4];
  #pragma unroll
  for (int ct = 0; ct < 4; ++ct){
    v1l[ct] = vf[10240 +   0 + ct*16 + p];
    v2l[ct] = vf[10240 +  64 + ct*16 + p];
    v3l[ct] = vf[10240 + 128 + ct*16 + p];
  }
  const float fcb = fc_b[0];
  __syncthreads();

  for (int it = blockIdx.x; it < NTASKS; it += GRID){
    const int b0 = it*16 + wv*4;                 // wave's 4 graphs: b0..b0+3
    const float adjv = adv;                      // adj[b0+g][i=p>>2][j=p&3] (prefetched)

    // -------- GEMM1: [Wh | fs fd] = x @ [W | waS waD] (16 x 80, K=256) --------
    f32x4 acc[4], acce;
    #pragma unroll
    for (int ct = 0; ct < 4; ++ct) acc[ct] = (f32x4){0.f,0.f,0.f,0.f};
    acce = (f32x4){0.f,0.f,0.f,0.f};
    #pragma unroll
    for (int kk = 0; kk < 8; ++kk){
      float4 f0 = xb[kk][0];
      float4 f1 = xb[kk][1];
      union { s16x8 v; __hip_bfloat162 h2[4]; } af;
      af.h2[0] = __float22bfloat162_rn(make_float2(f0.x, f0.y));
      af.h2[1] = __float22bfloat162_rn(make_float2(f0.z, f0.w));
      af.h2[2] = __float22bfloat162_rn(make_float2(f1.x, f1.y));
      af.h2[3] = __float22bfloat162_rn(make_float2(f1.z, f1.w));
      const int kb = kk*32 + g*8;
      #pragma unroll
      for (int ct = 0; ct < 4; ++ct){
        const int o = ct*16 + p;
        s16x8 bf = *(const s16x8*)&smem[o*256 + (kb ^ ((o & 7) << 3))];
        acc[ct] = __builtin_amdgcn_mfma_f32_16x16x32_bf16(af.v, bf, acc[ct], 0, 0, 0);
      }
      s16x8 ef = *(const s16x8*)&smem[16384 + p*256 + (kb ^ ((p & 7) << 3))];
      acce = __builtin_amdgcn_mfma_f32_16x16x32_bf16(af.v, ef, acce, 0, 0, 0);
    }
    // acc[ct][r] = Wh[4g+r][ct*16+p] ; acce[r] at lane(0,g)=fs[4g+r], lane(1,g)=fd[4g+r]

    // ---- issue next iteration's loads NOW; they fly during the epilogue ----
    {
      const int itn = it + GRID;
      if (itn < NTASKS){
        const int b0n = itn*16 + wv*4;
        const float* xrow = x + ((size_t)(b0n + (p >> 2))*4 + (p & 3))*256 + g*8;
        #pragma unroll
        for (int kk = 0; kk < 8; ++kk){
          xb[kk][0] = *(const float4*)(xrow + kk*32);
          xb[kk][1] = *(const float4*)(xrow + kk*32 + 4);
        }
        adv = adj[(size_t)(b0n + g)*16 + p];
      }
    }

    // -------- layer-1 attention (group g = graph b0+g) --------
    float fsr[4], fdr[4];
    #pragma unroll
    for (int r = 0; r < 4; ++r){
      fsr[r] = __shfl(acce[r], lbase + 0);
      fdr[r] = __shfl(acce[r], lbase + 1);
    }
    float fsi = (p & 8) ? ((p & 4) ? fsr[3] : fsr[2]) : ((p & 4) ? fsr[1] : fsr[0]);
    float fdj = (p & 2) ? ((p & 1) ? fdr[3] : fdr[2]) : ((p & 1) ? fdr[1] : fdr[0]);
    float ev = fsi + fdj;
    ev = (ev > 0.f) ? ev : LRELU_ALPHA*ev;
    ev = (adjv > 0.f) ? ev : NEG_INF;
    float mx = fmaxf(ev, __shfl_xor(ev, 1));
    mx = fmaxf(mx, __shfl_xor(mx, 2));
    float pe = __expf(ev - mx);
    float se = pe + __shfl_xor(pe, 1);
    se += __shfl_xor(se, 2);
    const float att = pe / se;   // att[i=p>>2][j=p&3] of graph b0+g

    // -------- hp = att @ Wh ; h1 = elu(hp), kept in f32 registers --------
    float h[4][4];  // h[ct][r] = h1[4g+r][ct*16+p]
    #pragma unroll
    for (int r = 0; r < 4; ++r){
      float b0a = __shfl(att, lbase + r*4 + 0);
      float b1a = __shfl(att, lbase + r*4 + 1);
      float b2a = __shfl(att, lbase + r*4 + 2);
      float b3a = __shfl(att, lbase + r*4 + 3);
      #pragma unroll
      for (int ct = 0; ct < 4; ++ct){
        float hp = b0a*acc[ct][0] + b1a*acc[ct][1] + b2a*acc[ct][2] + b3a*acc[ct][3];
        h[ct][r] = (hp > 0.f) ? hp : (__expf(hp) - 1.0f);
      }
    }

    // -------- layer 2 as GEMV: fs20, fd2[r], sv[r] = h1 . v{1,2,3} --------
    float fd2[4], sv[4], fs20 = 0.f;
    #pragma unroll
    for (int r = 0; r < 4; ++r){
      float s1 = 0.f, s2 = 0.f;
      #pragma unroll
      for (int ct = 0; ct < 4; ++ct){ s1 += h[ct][r]*v2l[ct]; s2 += h[ct][r]*v3l[ct]; }
      fd2[r] = s1; sv[r] = s2;
    }
    #pragma unroll
    for (int ct = 0; ct < 4; ++ct) fs20 += h[ct][0]*v1l[ct];
    #pragma unroll
    for (int msk = 1; msk < 16; msk <<= 1){
      #pragma unroll
      for (int r = 0; r < 4; ++r){
        fd2[r] += __shfl_xor(fd2[r], msk);
        sv[r]  += __shfl_xor(sv[r],  msk);
      }
      fs20 += __shfl_xor(fs20, msk);
    }

    // -------- layer-2 attention (row 0 only) + fc --------
    float e2[4];
    #pragma unroll
    for (int j = 0; j < 4; ++j){
      float adj0 = __shfl(adjv, lbase + j);     // adj[b][0][j]
      float tv = fs20 + fd2[j];
      tv = (tv > 0.f) ? tv : LRELU_ALPHA*tv;
      e2[j] = (adj0 > 0.f) ? tv : NEG_INF;
    }
    float m2 = fmaxf(fmaxf(e2[0], e2[1]), fmaxf(e2[2], e2[3]));
    float s2s = 0.f, ov = 0.f;
    #pragma unroll
    for (int j = 0; j < 4; ++j){
      float pj = __expf(e2[j] - m2);
      s2s += pj; ov += pj*sv[j];
    }
    if (p == 0) out[b0 + g] = ov/s2s + fcb;
  }
}

extern "C" void kernel_launch(void* const* d_in, const int* in_sizes, int n_in,
                              void* d_out, int out_size, void* d_ws, size_t ws_size,
                              hipStream_t stream){
  (void)in_sizes; (void)n_in; (void)out_size; (void)ws_size;
  const float* x   = (const float*)d_in[0];
  const float* adj = (const float*)d_in[1];
  const float* W   = (const float*)d_in[2];
  const float* a   = (const float*)d_in[3];
  const float* W2  = (const float*)d_in[4];
  const float* a2  = (const float*)d_in[5];
  const float* fcw = (const float*)d_in[6];
  const float* fcb = (const float*)d_in[7];
  float* out = (float*)d_out;
  unsigned short* wsp = (unsigned short*)d_ws;

  hipLaunchKernelGGL(prep_kernel, dim3(64), dim3(256), 0, stream, W, W2, a, a2, fcw, wsp);
  hipLaunchKernelGGL(gat_kernel, dim3(GRID), dim3(256), 0, stream,
                     x, adj, fcb, wsp, out);
}

// Round 5
// 113.446 us; speedup vs baseline: 1.4354x; 1.0611x over previous
//
#include <hip/hip_runtime.h>
#include <hip/hip_bf16.h>
#include <stdint.h>

#define LRELU_ALPHA 0.2f
#define NEG_INF -9000000000000000.0f
#define NB 32768
#define NTASKS (NB/16)
#define GRID 1024

typedef float f32x4 __attribute__((ext_vector_type(4)));
typedef short s16x8 __attribute__((ext_vector_type(8)));

__device__ __forceinline__ unsigned short f2bf(float f){
  unsigned int u = __float_as_uint(f);
  u += 0x7fffu + ((u >> 16) & 1u);   // round-to-nearest-even
  return (unsigned short)(u >> 16);
}

// ws layout: ushort [0,16384): W^T bf16 swizzled (64 cols x 256 k)
//            ushort [16384,20480): e-tile bf16 swizzled (16 cols x 256 k; col0=W@aS, col1=W@aD, rest 0)
//            float  [10240,10432) (byte 40960+): v1,v2,v3 = W2eff @ {a2S, a2D, fc_w} (3 x 64 f32)
__global__ void prep_kernel(const float* __restrict__ W, const float* __restrict__ W2,
                            const float* __restrict__ a, const float* __restrict__ a2,
                            const float* __restrict__ fc_w,
                            unsigned short* __restrict__ wsp){
  int t = blockIdx.x * blockDim.x + threadIdx.x;
  if (t < 64*256){
    int o = t & 63, k = t >> 6;
    wsp[o*256 + (k ^ ((o & 7) << 3))] = f2bf(W[k*64 + o]);
  }
  if (t < 16*256){
    int o = t & 15, k = t >> 4;
    float v = 0.f;
    if (o == 0){ for (int c = 0; c < 64; ++c) v += W[k*64 + c]*a[c]; }
    else if (o == 1){ for (int c = 0; c < 64; ++c) v += W[k*64 + c]*a[64 + c]; }
    wsp[16384 + o*256 + (k ^ ((o & 7) << 3))] = f2bf(v);
  }
  if (t < 192){
    int which = t >> 6, c = t & 63;
    const float* vec = (which == 0) ? a2 : (which == 1) ? (a2 + 64) : fc_w;
    float s = 0.f;
    for (int o = 0; o < 64; ++o){
      float w2e = 0.f;
      #pragma unroll
      for (int h = 0; h < 8; ++h) w2e += W2[(h*64 + c)*64 + o];
      s += w2e * vec[o];
    }
    ((float*)wsp)[10240 + t] = s;
  }
}

// No register prefetch buffer: rely on TLP (4 blocks/CU, LDS=160KB exactly) to
// hide HBM latency. Arch-VGPR demand ~60 << 64 (half of the 128 cap after the
// compiler's VGPR/AGPR split), so no scratch spill.
__launch_bounds__(256, 4)
__global__ void gat_kernel(const float* __restrict__ x, const float* __restrict__ adj,
                           const float* __restrict__ fc_b,
                           const unsigned short* __restrict__ wsp,
                           float* __restrict__ out){
  // LDS: [0,16384) W^T ; [16384,20480) e-tile  (40 KB -> 4 blocks/CU)
  __shared__ __align__(16) unsigned short smem[20480];
  const int tid = threadIdx.x;
  const int p  = tid & 15;        // A-row / B-col / C-col lane index
  const int g  = (tid >> 4) & 3;  // 16-lane group within wave (owns graph g)
  const int wv = tid >> 6;        // wave id in block
  const int lbase = tid & 48;     // wave-relative group base lane

  // ---- stage W + e-tile into LDS (L2-resident source) ----
  {
    const uint4* src = (const uint4*)wsp;
    uint4* dst = (uint4*)smem;
    #pragma unroll
    for (int i = 0; i < 10; ++i) dst[tid + 256*i] = src[tid + 256*i];
  }

  // per-lane GEMV vectors for layer 2
  const float* vf = (const float*)wsp;
  float v1l[4], v2l[4], v3l[4];
  #pragma unroll
  for (int ct = 0; ct < 4; ++ct){
    v1l[ct] = vf[10240 +   0 + ct*16 + p];
    v2l[ct] = vf[10240 +  64 + ct*16 + p];
    v3l[ct] = vf[10240 + 128 + ct*16 + p];
  }
  const float fcb = fc_b[0];
  __syncthreads();

  for (int it = blockIdx.x; it < NTASKS; it += GRID){
    const int b0 = it*16 + wv*4;                      // wave's 4 graphs: b0..b0+3
    const float adjv = adj[(size_t)(b0 + g)*16 + p];  // adj[b0+g][i=p>>2][j=p&3]

    // -------- GEMM1: [Wh | fs fd] = x @ [W | waS waD] (16 x 80, K=256) --------
    f32x4 acc[4], acce;
    #pragma unroll
    for (int ct = 0; ct < 4; ++ct) acc[ct] = (f32x4){0.f,0.f,0.f,0.f};
    acce = (f32x4){0.f,0.f,0.f,0.f};
    const float* xrow = x + (size_t)(b0*4 + p)*256 + g*8;
    #pragma unroll
    for (int kk = 0; kk < 8; ++kk){
      float4 f0 = *(const float4*)(xrow + kk*32);
      float4 f1 = *(const float4*)(xrow + kk*32 + 4);
      union { s16x8 v; __hip_bfloat162 h2[4]; } af;
      af.h2[0] = __float22bfloat162_rn(make_float2(f0.x, f0.y));
      af.h2[1] = __float22bfloat162_rn(make_float2(f0.z, f0.w));
      af.h2[2] = __float22bfloat162_rn(make_float2(f1.x, f1.y));
      af.h2[3] = __float22bfloat162_rn(make_float2(f1.z, f1.w));
      const int kb = kk*32 + g*8;
      #pragma unroll
      for (int ct = 0; ct < 4; ++ct){
        const int o = ct*16 + p;
        s16x8 bf = *(const s16x8*)&smem[o*256 + (kb ^ ((o & 7) << 3))];
        acc[ct] = __builtin_amdgcn_mfma_f32_16x16x32_bf16(af.v, bf, acc[ct], 0, 0, 0);
      }
      s16x8 ef = *(const s16x8*)&smem[16384 + p*256 + (kb ^ ((p & 7) << 3))];
      acce = __builtin_amdgcn_mfma_f32_16x16x32_bf16(af.v, ef, acce, 0, 0, 0);
    }
    // acc[ct][r] = Wh[4g+r][ct*16+p] ; acce[r] at lane(0,g)=fs[4g+r], lane(1,g)=fd[4g+r]

    // -------- layer-1 attention (group g = graph b0+g) --------
    float fsr[4], fdr[4];
    #pragma unroll
    for (int r = 0; r < 4; ++r){
      fsr[r] = __shfl(acce[r], lbase + 0);
      fdr[r] = __shfl(acce[r], lbase + 1);
    }
    float fsi = (p & 8) ? ((p & 4) ? fsr[3] : fsr[2]) : ((p & 4) ? fsr[1] : fsr[0]);
    float fdj = (p & 2) ? ((p & 1) ? fdr[3] : fdr[2]) : ((p & 1) ? fdr[1] : fdr[0]);
    float ev = fsi + fdj;
    ev = (ev > 0.f) ? ev : LRELU_ALPHA*ev;
    ev = (adjv > 0.f) ? ev : NEG_INF;
    float mx = fmaxf(ev, __shfl_xor(ev, 1));
    mx = fmaxf(mx, __shfl_xor(mx, 2));
    float pe = __expf(ev - mx);
    float se = pe + __shfl_xor(pe, 1);
    se += __shfl_xor(se, 2);
    const float att = pe / se;   // att[i=p>>2][j=p&3] of graph b0+g

    // -------- hp = att @ Wh ; h1 = elu(hp), kept in f32 registers --------
    float h[4][4];  // h[ct][r] = h1[4g+r][ct*16+p]
    #pragma unroll
    for (int r = 0; r < 4; ++r){
      float b0a = __shfl(att, lbase + r*4 + 0);
      float b1a = __shfl(att, lbase + r*4 + 1);
      float b2a = __shfl(att, lbase + r*4 + 2);
      float b3a = __shfl(att, lbase + r*4 + 3);
      #pragma unroll
      for (int ct = 0; ct < 4; ++ct){
        float hp = b0a*acc[ct][0] + b1a*acc[ct][1] + b2a*acc[ct][2] + b3a*acc[ct][3];
        h[ct][r] = (hp > 0.f) ? hp : (__expf(hp) - 1.0f);
      }
    }

    // -------- layer 2 as GEMV: fs20, fd2[r], sv[r] = h1 . v{1,2,3} --------
    float fd2[4], sv[4], fs20 = 0.f;
    #pragma unroll
    for (int r = 0; r < 4; ++r){
      float s1 = 0.f, s2 = 0.f;
      #pragma unroll
      for (int ct = 0; ct < 4; ++ct){ s1 += h[ct][r]*v2l[ct]; s2 += h[ct][r]*v3l[ct]; }
      fd2[r] = s1; sv[r] = s2;
    }
    #pragma unroll
    for (int ct = 0; ct < 4; ++ct) fs20 += h[ct][0]*v1l[ct];
    #pragma unroll
    for (int msk = 1; msk < 16; msk <<= 1){
      #pragma unroll
      for (int r = 0; r < 4; ++r){
        fd2[r] += __shfl_xor(fd2[r], msk);
        sv[r]  += __shfl_xor(sv[r],  msk);
      }
      fs20 += __shfl_xor(fs20, msk);
    }

    // -------- layer-2 attention (row 0 only) + fc --------
    float e2[4];
    #pragma unroll
    for (int j = 0; j < 4; ++j){
      float adj0 = __shfl(adjv, lbase + j);     // adj[b][0][j]
      float tv = fs20 + fd2[j];
      tv = (tv > 0.f) ? tv : LRELU_ALPHA*tv;
      e2[j] = (adj0 > 0.f) ? tv : NEG_INF;
    }
    float m2 = fmaxf(fmaxf(e2[0], e2[1]), fmaxf(e2[2], e2[3]));
    float s2s = 0.f, ov = 0.f;
    #pragma unroll
    for (int j = 0; j < 4; ++j){
      float pj = __expf(e2[j] - m2);
      s2s += pj; ov += pj*sv[j];
    }
    if (p == 0) out[b0 + g] = ov/s2s + fcb;
  }
}

extern "C" void kernel_launch(void* const* d_in, const int* in_sizes, int n_in,
                              void* d_out, int out_size, void* d_ws, size_t ws_size,
                              hipStream_t stream){
  (void)in_sizes; (void)n_in; (void)out_size; (void)ws_size;
  const float* x   = (const float*)d_in[0];
  const float* adj = (const float*)d_in[1];
  const float* W   = (const float*)d_in[2];
  const float* a   = (const float*)d_in[3];
  const float* W2  = (const float*)d_in[4];
  const float* a2  = (const float*)d_in[5];
  const float* fcw = (const float*)d_in[6];
  const float* fcb = (const float*)d_in[7];
  float* out = (float*)d_out;
  unsigned short* wsp = (unsigned short*)d_ws;

  hipLaunchKernelGGL(prep_kernel, dim3(64), dim3(256), 0, stream, W, W2, a, a2, fcw, wsp);
  hipLaunchKernelGGL(gat_kernel, dim3(GRID), dim3(256), 0, stream,
                     x, adj, fcb, wsp, out);
}

// Round 6
// 55.630 us; speedup vs baseline: 2.9273x; 2.0393x over previous
//
#include <hip/hip_runtime.h>
#include <hip/hip_bf16.h>
#include <stdint.h>

#define LRELU_ALPHA 0.2f
#define NEG_INF -9000000000000000.0f
#define NB 32768
#define NTASKS (NB/16)
#define GRID 1024

typedef float f32x4 __attribute__((ext_vector_type(4)));
typedef short s16x8 __attribute__((ext_vector_type(8)));

__device__ __forceinline__ unsigned short f2bf(float f){
  unsigned int u = __float_as_uint(f);
  u += 0x7fffu + ((u >> 16) & 1u);   // round-to-nearest-even
  return (unsigned short)(u >> 16);
}

// ws layout: ushort [0,16384): W^T bf16 swizzled (64 cols x 256 k)
//            ushort [16384,20480): e-tile bf16 swizzled (16 cols x 256 k; col0=W@aS, col1=W@aD, rest 0)
//            float  [10240,10432) (byte 40960+): v1,v2,v3 = W2eff @ {a2S, a2D, fc_w} (3 x 64 f32)
__global__ void prep_kernel(const float* __restrict__ W, const float* __restrict__ W2,
                            const float* __restrict__ a, const float* __restrict__ a2,
                            const float* __restrict__ fc_w,
                            unsigned short* __restrict__ wsp){
  int t = blockIdx.x * blockDim.x + threadIdx.x;
  if (t < 64*256){
    int o = t & 63, k = t >> 6;
    wsp[o*256 + (k ^ ((o & 7) << 3))] = f2bf(W[k*64 + o]);
  }
  if (t < 16*256){
    int o = t & 15, k = t >> 4;
    float v = 0.f;
    if (o == 0){ for (int c = 0; c < 64; ++c) v += W[k*64 + c]*a[c]; }
    else if (o == 1){ for (int c = 0; c < 64; ++c) v += W[k*64 + c]*a[64 + c]; }
    wsp[16384 + o*256 + (k ^ ((o & 7) << 3))] = f2bf(v);
  }
  if (t < 192){
    int which = t >> 6, c = t & 63;
    const float* vec = (which == 0) ? a2 : (which == 1) ? (a2 + 64) : fc_w;
    float s = 0.f;
    for (int o = 0; o < 64; ++o){
      float w2e = 0.f;
      #pragma unroll
      for (int h = 0; h < 8; ++h) w2e += W2[(h*64 + c)*64 + o];
      s += w2e * vec[o];
    }
    ((float*)wsp)[10240 + t] = s;
  }
}

// Spill-proof version: kk loop unrolled only 2x so at most 4 float4 global
// loads are in flight (16 VGPRs), keeping arch-VGPR demand under the ~64
// half-budget the allocator grants MFMA kernels at 4 waves/EU. Latency is
// hidden by TLP (16 waves/CU), not by hoisted loads.
__launch_bounds__(256, 4)
__global__ void gat_kernel(const float* __restrict__ x, const float* __restrict__ adj,
                           const float* __restrict__ fc_b,
                           const unsigned short* __restrict__ wsp,
                           float* __restrict__ out){
  // LDS: [0,16384) W^T ; [16384,20480) e-tile  (40 KB -> 4 blocks/CU)
  __shared__ __align__(16) unsigned short smem[20480];
  const int tid = threadIdx.x;
  const int p  = tid & 15;        // A-row / B-col / C-col lane index
  const int g  = (tid >> 4) & 3;  // 16-lane group within wave (owns graph g)
  const int wv = tid >> 6;        // wave id in block
  const int lbase = tid & 48;     // wave-relative group base lane

  // ---- stage W + e-tile into LDS (L2-resident source) ----
  {
    const uint4* src = (const uint4*)wsp;
    uint4* dst = (uint4*)smem;
    #pragma unroll
    for (int i = 0; i < 10; ++i) dst[tid + 256*i] = src[tid + 256*i];
  }

  // per-lane GEMV vectors for layer 2
  const float* vf = (const float*)wsp;
  float v1l[4], v2l[4], v3l[4];
  #pragma unroll
  for (int ct = 0; ct < 4; ++ct){
    v1l[ct] = vf[10240 +   0 + ct*16 + p];
    v2l[ct] = vf[10240 +  64 + ct*16 + p];
    v3l[ct] = vf[10240 + 128 + ct*16 + p];
  }
  const float fcb = fc_b[0];
  __syncthreads();

  for (int it = blockIdx.x; it < NTASKS; it += GRID){
    const int b0 = it*16 + wv*4;                      // wave's 4 graphs: b0..b0+3
    const float adjv = adj[(size_t)(b0 + g)*16 + p];  // adj[b0+g][i=p>>2][j=p&3]

    // -------- GEMM1: [Wh | fs fd] = x @ [W | waS waD] (16 x 80, K=256) --------
    f32x4 acc[4], acce;
    #pragma unroll
    for (int ct = 0; ct < 4; ++ct) acc[ct] = (f32x4){0.f,0.f,0.f,0.f};
    acce = (f32x4){0.f,0.f,0.f,0.f};
    const float* xrow = x + (size_t)(b0*4 + p)*256 + g*8;
    #pragma unroll 2
    for (int kk = 0; kk < 8; ++kk){
      float4 f0 = *(const float4*)(xrow + kk*32);
      float4 f1 = *(const float4*)(xrow + kk*32 + 4);
      union { s16x8 v; __hip_bfloat162 h2[4]; } af;
      af.h2[0] = __float22bfloat162_rn(make_float2(f0.x, f0.y));
      af.h2[1] = __float22bfloat162_rn(make_float2(f0.z, f0.w));
      af.h2[2] = __float22bfloat162_rn(make_float2(f1.x, f1.y));
      af.h2[3] = __float22bfloat162_rn(make_float2(f1.z, f1.w));
      const int kb = kk*32 + g*8;
      #pragma unroll
      for (int ct = 0; ct < 4; ++ct){
        const int o = ct*16 + p;
        s16x8 bf = *(const s16x8*)&smem[o*256 + (kb ^ ((o & 7) << 3))];
        acc[ct] = __builtin_amdgcn_mfma_f32_16x16x32_bf16(af.v, bf, acc[ct], 0, 0, 0);
      }
      s16x8 ef = *(const s16x8*)&smem[16384 + p*256 + (kb ^ ((p & 7) << 3))];
      acce = __builtin_amdgcn_mfma_f32_16x16x32_bf16(af.v, ef, acce, 0, 0, 0);
    }
    // acc[ct][r] = Wh[4g+r][ct*16+p] ; acce[r] at lane(0,g)=fs[4g+r], lane(1,g)=fd[4g+r]

    // -------- layer-1 attention (group g = graph b0+g) --------
    float fsr[4], fdr[4];
    #pragma unroll
    for (int r = 0; r < 4; ++r){
      fsr[r] = __shfl(acce[r], lbase + 0);
      fdr[r] = __shfl(acce[r], lbase + 1);
    }
    float fsi = (p & 8) ? ((p & 4) ? fsr[3] : fsr[2]) : ((p & 4) ? fsr[1] : fsr[0]);
    float fdj = (p & 2) ? ((p & 1) ? fdr[3] : fdr[2]) : ((p & 1) ? fdr[1] : fdr[0]);
    float ev = fsi + fdj;
    ev = (ev > 0.f) ? ev : LRELU_ALPHA*ev;
    ev = (adjv > 0.f) ? ev : NEG_INF;
    float mx = fmaxf(ev, __shfl_xor(ev, 1));
    mx = fmaxf(mx, __shfl_xor(mx, 2));
    float pe = __expf(ev - mx);
    float se = pe + __shfl_xor(pe, 1);
    se += __shfl_xor(se, 2);
    const float att = pe / se;   // att[i=p>>2][j=p&3] of graph b0+g

    // -------- hp = att @ Wh ; h1 = elu(hp), kept in f32 registers --------
    float h[4][4];  // h[ct][r] = h1[4g+r][ct*16+p]
    #pragma unroll
    for (int r = 0; r < 4; ++r){
      float b0a = __shfl(att, lbase + r*4 + 0);
      float b1a = __shfl(att, lbase + r*4 + 1);
      float b2a = __shfl(att, lbase + r*4 + 2);
      float b3a = __shfl(att, lbase + r*4 + 3);
      #pragma unroll
      for (int ct = 0; ct < 4; ++ct){
        float hp = b0a*acc[ct][0] + b1a*acc[ct][1] + b2a*acc[ct][2] + b3a*acc[ct][3];
        h[ct][r] = (hp > 0.f) ? hp : (__expf(hp) - 1.0f);
      }
    }

    // -------- layer 2 as GEMV: fs20, fd2[r], sv[r] = h1 . v{1,2,3} --------
    float fd2[4], sv[4], fs20 = 0.f;
    #pragma unroll
    for (int r = 0; r < 4; ++r){
      float s1 = 0.f, s2 = 0.f;
      #pragma unroll
      for (int ct = 0; ct < 4; ++ct){ s1 += h[ct][r]*v2l[ct]; s2 += h[ct][r]*v3l[ct]; }
      fd2[r] = s1; sv[r] = s2;
    }
    #pragma unroll
    for (int ct = 0; ct < 4; ++ct) fs20 += h[ct][0]*v1l[ct];
    #pragma unroll
    for (int msk = 1; msk < 16; msk <<= 1){
      #pragma unroll
      for (int r = 0; r < 4; ++r){
        fd2[r] += __shfl_xor(fd2[r], msk);
        sv[r]  += __shfl_xor(sv[r],  msk);
      }
      fs20 += __shfl_xor(fs20, msk);
    }

    // -------- layer-2 attention (row 0 only) + fc --------
    float e2[4];
    #pragma unroll
    for (int j = 0; j < 4; ++j){
      float adj0 = __shfl(adjv, lbase + j);     // adj[b][0][j]
      float tv = fs20 + fd2[j];
      tv = (tv > 0.f) ? tv : LRELU_ALPHA*tv;
      e2[j] = (adj0 > 0.f) ? tv : NEG_INF;
    }
    float m2 = fmaxf(fmaxf(e2[0], e2[1]), fmaxf(e2[2], e2[3]));
    float s2s = 0.f, ov = 0.f;
    #pragma unroll
    for (int j = 0; j < 4; ++j){
      float pj = __expf(e2[j] - m2);
      s2s += pj; ov += pj*sv[j];
    }
    if (p == 0) out[b0 + g] = ov/s2s + fcb;
  }
}

extern "C" void kernel_launch(void* const* d_in, const int* in_sizes, int n_in,
                              void* d_out, int out_size, void* d_ws, size_t ws_size,
                              hipStream_t stream){
  (void)in_sizes; (void)n_in; (void)out_size; (void)ws_size;
  const float* x   = (const float*)d_in[0];
  const float* adj = (const float*)d_in[1];
  const float* W   = (const float*)d_in[2];
  const float* a   = (const float*)d_in[3];
  const float* W2  = (const float*)d_in[4];
  const float* a2  = (const float*)d_in[5];
  const float* fcw = (const float*)d_in[6];
  const float* fcb = (const float*)d_in[7];
  float* out = (float*)d_out;
  unsigned short* wsp = (unsigned short*)d_ws;

  hipLaunchKernelGGL(prep_kernel, dim3(64), dim3(256), 0, stream, W, W2, a, a2, fcw, wsp);
  hipLaunchKernelGGL(gat_kernel, dim3(GRID), dim3(256), 0, stream,
                     x, adj, fcb, wsp, out);
}